// Round 1
// baseline (227.098 us; speedup 1.0000x reference)
//
#include <hip/hip_runtime.h>

typedef __attribute__((ext_vector_type(4))) float  f32x4;
typedef __attribute__((ext_vector_type(8))) short  s16x8;
typedef __attribute__((ext_vector_type(4))) short  s16x4;

#define THR_  1.0e-4f   // LR * GAMMA
#define SC_   2.0e-3f   // 2 * LR

__device__ __forceinline__ unsigned short f2bf(float f) {
  unsigned u = __builtin_bit_cast(unsigned, f);
  u += 0x7FFFu + ((u >> 16) & 1u);          // round-to-nearest-even
  return (unsigned short)(u >> 16);
}

__device__ __forceinline__ float sthr(float v) {
  return fmaxf(v - THR_, 0.0f) + fminf(v + THR_, 0.0f);
}

// ws layout (unsigned short elems):
//   [0     , 65536)  Gpk : B-frags of (-2LR * W@W^T), K=256,N=256 (kc 0..7, nt 0..15)
//   [65536 , 98304)  WTpk: B-frags of ( 2LR * W^T),   K=128,N=256 (kc 0..3, nt 0..15)
//   [98304 ,131072)  Wpk : B-frags of W,              K=256,N=128 (kc 0..7, nt 0..7)
// B-frag packing: elem j of lane l of frag (kc,nt) = M[kc*32 + (l>>4)*8 + j][nt*16 + (l&15)]
__global__ void sc_prep(const float* __restrict__ W, unsigned short* __restrict__ ws) {
  const int b = blockIdx.x;
  const int l = threadIdx.x;
  const int g = l >> 4, c = l & 15;
  if (b < 128) {                       // Gpk
    const int kc = b >> 4, nt = b & 15;
    const int n = nt * 16 + c;
    const int k0 = kc * 32 + g * 8;
    float s[8];
    #pragma unroll
    for (int j = 0; j < 8; ++j) s[j] = 0.0f;
    for (int i = 0; i < 128; ++i) {
      const float wn = W[n * 128 + i];
      #pragma unroll
      for (int j = 0; j < 8; ++j) s[j] += W[(k0 + j) * 128 + i] * wn;
    }
    unsigned short* dst = ws + ((unsigned)b * 64u + l) * 8u;
    #pragma unroll
    for (int j = 0; j < 8; ++j) dst[j] = f2bf(-SC_ * s[j]);
  } else if (b < 192) {                // WTpk
    const int bb = b - 128;
    const int kc = bb >> 4, nt = bb & 15;
    const int n = nt * 16 + c;         // o index
    const int k0 = kc * 32 + g * 8;    // i index base
    unsigned short* dst = ws + 65536u + ((unsigned)bb * 64u + l) * 8u;
    #pragma unroll
    for (int j = 0; j < 8; ++j) dst[j] = f2bf(SC_ * W[n * 128 + (k0 + j)]);
  } else {                             // Wpk
    const int bb = b - 192;
    const int kc = bb >> 3, nt = bb & 7;
    const int n = nt * 16 + c;         // i index (out col)
    const int k0 = kc * 32 + g * 8;    // o index base
    unsigned short* dst = ws + 98304u + ((unsigned)bb * 64u + l) * 8u;
    #pragma unroll
    for (int j = 0; j < 8; ++j) dst[j] = f2bf(W[(k0 + j) * 128 + n]);
  }
}

// 8 waves, 64 batch rows/block, 32 n-cols per wave; G slice register-resident;
// x: f32 in regs (accumulator positions) + bf16 double-buffered swizzled LDS (A layout).
__global__ __launch_bounds__(512, 2) void sc_fused(
    const float* __restrict__ inp,
    const unsigned short* __restrict__ wsp,
    float* __restrict__ outp)
{
  __shared__ unsigned char lds[81920];   // XB0 [0,32K), XB1 [32K,64K), INB [64K,80K)
  unsigned char* const INB = lds + 65536;

  const int tid = threadIdx.x;
  const int l = tid & 63;
  const int w = tid >> 6;
  const int g = l >> 4;
  const int c = l & 15;
  const long row0 = (long)blockIdx.x * 64;

  // ---- stage inputs -> INB (bf16, row-XOR swizzle) ----
  #pragma unroll
  for (int rep = 0; rep < 4; ++rep) {
    const int flat = rep * 512 + tid;           // 0..2047 float4s
    const int r = flat >> 5;                    // row 0..63
    const int c4 = flat & 31;
    const f32x4 v = *reinterpret_cast<const f32x4*>(inp + (row0 + r) * 128 + c4 * 4);
    s16x4 p;
    p[0] = (short)f2bf(v[0]); p[1] = (short)f2bf(v[1]);
    p[2] = (short)f2bf(v[2]); p[3] = (short)f2bf(v[3]);
    const int sw = (c4 * 8) ^ ((r & 7) << 4);
    *reinterpret_cast<s16x4*>(INB + r * 256 + sw) = p;
  }

  // ---- B-frags for c-phase (2LR * W^T), 2 n-tiles for this wave ----
  s16x8 bfrag[16];
  #pragma unroll
  for (int kc = 0; kc < 4; ++kc)
    #pragma unroll
    for (int n = 0; n < 2; ++n)
      bfrag[kc * 2 + n] = *reinterpret_cast<const s16x8*>(
          wsp + 65536u + ((unsigned)(kc * 16 + (w * 2 + n)) * 64u + l) * 8u);

  __syncthreads();

  // ---- c = 2LR * in @ W^T ----
  f32x4 acc[4][2];
  #pragma unroll
  for (int rt = 0; rt < 4; ++rt)
    #pragma unroll
    for (int n = 0; n < 2; ++n)
      acc[rt][n] = (f32x4){0.f, 0.f, 0.f, 0.f};

  #pragma unroll
  for (int kc = 0; kc < 4; ++kc) {
    s16x8 a[4];
    #pragma unroll
    for (int rt = 0; rt < 4; ++rt) {
      const int row = rt * 16 + c;
      const int sw = (kc * 64 + g * 16) ^ ((row & 7) << 4);
      a[rt] = *reinterpret_cast<const s16x8*>(INB + row * 256 + sw);
    }
    #pragma unroll
    for (int rt = 0; rt < 4; ++rt)
      #pragma unroll
      for (int n = 0; n < 2; ++n)
        acc[rt][n] = __builtin_amdgcn_mfma_f32_16x16x32_bf16(
            a[rt], bfrag[kc * 2 + n], acc[rt][n], 0, 0, 0);
  }

  f32x4 creg[4][2], xreg[4][2];
  #pragma unroll
  for (int rt = 0; rt < 4; ++rt)
    #pragma unroll
    for (int n = 0; n < 2; ++n) {
      creg[rt][n] = acc[rt][n];
      #pragma unroll
      for (int r = 0; r < 4; ++r) xreg[rt][n][r] = sthr(acc[rt][n][r]);
    }

  // write x1 -> XB0 (bf16, swizzled)
  #pragma unroll
  for (int rt = 0; rt < 4; ++rt)
    #pragma unroll
    for (int n = 0; n < 2; ++n)
      #pragma unroll
      for (int r = 0; r < 4; ++r) {
        const int row = rt * 16 + g * 4 + r;
        const int col = w * 32 + n * 16 + c;
        const int sw = (col * 2) ^ ((row & 7) << 4);
        *reinterpret_cast<unsigned short*>(lds + row * 512 + sw) = f2bf(xreg[rt][n][r]);
      }

  // ---- B-frags for steps (-2LR * G) ----
  #pragma unroll
  for (int kc = 0; kc < 8; ++kc)
    #pragma unroll
    for (int n = 0; n < 2; ++n)
      bfrag[kc * 2 + n] = *reinterpret_cast<const s16x8*>(
          wsp + ((unsigned)(kc * 16 + (w * 2 + n)) * 64u + l) * 8u);

  // ---- 9 remaining ISTA steps: x <- sthr(x + c - 2LR*(x@G)) ----
  int cur = 0;
  for (int step = 0; step < 9; ++step) {
    __syncthreads();                       // prev writes visible / prev reads done
    const unsigned char* xb = lds + (cur << 15);
    #pragma unroll
    for (int rt = 0; rt < 4; ++rt)
      #pragma unroll
      for (int n = 0; n < 2; ++n)
        acc[rt][n] = creg[rt][n] + xreg[rt][n];
    #pragma unroll
    for (int kc = 0; kc < 8; ++kc) {
      s16x8 a[4];
      #pragma unroll
      for (int rt = 0; rt < 4; ++rt) {
        const int row = rt * 16 + c;
        const int sw = (kc * 64 + g * 16) ^ ((row & 7) << 4);
        a[rt] = *reinterpret_cast<const s16x8*>(xb + row * 512 + sw);
      }
      #pragma unroll
      for (int rt = 0; rt < 4; ++rt)
        #pragma unroll
        for (int n = 0; n < 2; ++n)
          acc[rt][n] = __builtin_amdgcn_mfma_f32_16x16x32_bf16(
              a[rt], bfrag[kc * 2 + n], acc[rt][n], 0, 0, 0);
    }
    #pragma unroll
    for (int rt = 0; rt < 4; ++rt)
      #pragma unroll
      for (int n = 0; n < 2; ++n)
        #pragma unroll
        for (int r = 0; r < 4; ++r)
          xreg[rt][n][r] = sthr(acc[rt][n][r]);
    cur ^= 1;
    unsigned char* xn = lds + (cur << 15);
    #pragma unroll
    for (int rt = 0; rt < 4; ++rt)
      #pragma unroll
      for (int n = 0; n < 2; ++n)
        #pragma unroll
        for (int r = 0; r < 4; ++r) {
          const int row = rt * 16 + g * 4 + r;
          const int col = w * 32 + n * 16 + c;
          const int sw = (col * 2) ^ ((row & 7) << 4);
          *reinterpret_cast<unsigned short*>(xn + row * 512 + sw) = f2bf(xreg[rt][n][r]);
        }
  }

  // ---- out = x @ W ; wave w owns out cols [w*16, w*16+16) ----
  __syncthreads();
  const unsigned char* xb = lds + (cur << 15);
  s16x8 wfr[8];
  #pragma unroll
  for (int kc = 0; kc < 8; ++kc)
    wfr[kc] = *reinterpret_cast<const s16x8*>(
        wsp + 98304u + ((unsigned)(kc * 8 + w) * 64u + l) * 8u);
  f32x4 oacc[4];
  #pragma unroll
  for (int rt = 0; rt < 4; ++rt) oacc[rt] = (f32x4){0.f, 0.f, 0.f, 0.f};
  #pragma unroll
  for (int kc = 0; kc < 8; ++kc) {
    s16x8 a[4];
    #pragma unroll
    for (int rt = 0; rt < 4; ++rt) {
      const int row = rt * 16 + c;
      const int sw = (kc * 64 + g * 16) ^ ((row & 7) << 4);
      a[rt] = *reinterpret_cast<const s16x8*>(xb + row * 512 + sw);
    }
    #pragma unroll
    for (int rt = 0; rt < 4; ++rt)
      oacc[rt] = __builtin_amdgcn_mfma_f32_16x16x32_bf16(a[rt], wfr[kc], oacc[rt], 0, 0, 0);
  }
  #pragma unroll
  for (int rt = 0; rt < 4; ++rt)
    #pragma unroll
    for (int r = 0; r < 4; ++r)
      outp[(row0 + rt * 16 + g * 4 + r) * 128 + w * 16 + c] = oacc[rt][r];
}

extern "C" void kernel_launch(void* const* d_in, const int* in_sizes, int n_in,
                              void* d_out, int out_size, void* d_ws, size_t ws_size,
                              hipStream_t stream) {
  const float* inp = (const float*)d_in[0];
  const float* W   = (const float*)d_in[1];
  unsigned short* ws = (unsigned short*)d_ws;   // needs 256 KiB
  float* outp = (float*)d_out;
  const int B = in_sizes[0] / 128;              // 131072
  sc_prep<<<256, 64, 0, stream>>>(W, ws);
  sc_fused<<<B / 64, 512, 0, stream>>>(inp, ws, outp);
}